// Round 1
// baseline (2999.097 us; speedup 1.0000x reference)
//
#include <hip/hip_runtime.h>
#include <math.h>

#define NFFT 8192
#define LOG2N 13
constexpr int DMODEL = 1024;
constexpr int NSEQ = 8192;

// ---------------------------------------------------------------------------
// GEMM: C[r][c] = sum_k A[r][k] * B[c][k]  (both row-major along k)
// transA: A stored as At[k][r] (lda = row stride over k)
// biasMode: 0 none, 1 bias[r], 2 bias[c]
// ---------------------------------------------------------------------------
__global__ __launch_bounds__(256) void gemm_rr(
    const float* __restrict__ A, const float* __restrict__ B,
    const float* __restrict__ bias, float* __restrict__ C,
    int lda, int ldb, int ldc,
    long long aBS, long long bBS, long long cBS,
    int biasMode, int transA)
{
  __shared__ float As[16][68];   // [k][r], padded: 68*4B % 16B == 0, low bank conflict
  __shared__ float Bs[16][68];   // [k][c]
  const int bx = blockIdx.x, by = blockIdx.y, bz = blockIdx.z;
  A += (long long)bz * aBS;
  B += (long long)bz * bBS;
  C += (long long)bz * cBS;
  const int t = threadIdx.x;
  const int tx = t & 15, ty = t >> 4;
  const int r0 = by * 64, c0 = bx * 64;

  float acc[4][4];
#pragma unroll
  for (int i = 0; i < 4; ++i)
#pragma unroll
    for (int j = 0; j < 4; ++j) acc[i][j] = 0.f;

  for (int k0 = 0; k0 < 1024; k0 += 16) {
    if (!transA) {
#pragma unroll
      for (int p = 0; p < 4; ++p) {
        int idx = t + p * 256;
        int i = idx >> 4, k = idx & 15;
        As[k][i] = A[(long long)(r0 + i) * lda + k0 + k];
      }
    } else {
#pragma unroll
      for (int p = 0; p < 4; ++p) {
        int idx = t + p * 256;
        int k = idx >> 6, i = idx & 63;
        As[k][i] = A[(long long)(k0 + k) * lda + r0 + i];
      }
    }
#pragma unroll
    for (int p = 0; p < 4; ++p) {
      int idx = t + p * 256;
      int j = idx >> 4, k = idx & 15;
      Bs[k][j] = B[(long long)(c0 + j) * ldb + k0 + k];
    }
    __syncthreads();
#pragma unroll
    for (int k = 0; k < 16; ++k) {
      const float4 a4 = *(const float4*)&As[k][ty * 4];
      const float4 b4 = *(const float4*)&Bs[k][tx * 4];
      float a[4] = {a4.x, a4.y, a4.z, a4.w};
      float b[4] = {b4.x, b4.y, b4.z, b4.w};
#pragma unroll
      for (int i = 0; i < 4; ++i)
#pragma unroll
        for (int j = 0; j < 4; ++j) acc[i][j] += a[i] * b[j];
    }
    __syncthreads();
  }

#pragma unroll
  for (int i = 0; i < 4; ++i) {
    const int r = r0 + ty * 4 + i;
    const int c = c0 + tx * 4;
    float4 v = make_float4(acc[i][0], acc[i][1], acc[i][2], acc[i][3]);
    if (biasMode == 1) {
      const float bb = bias[r];
      v.x += bb; v.y += bb; v.z += bb; v.w += bb;
    } else if (biasMode == 2) {
      v.x += bias[c]; v.y += bias[c + 1]; v.z += bias[c + 2]; v.w += bias[c + 3];
    }
    *(float4*)&C[(long long)r * ldc + c] = v;
  }
}

// ---------------------------------------------------------------------------
// In-LDS radix-2 DIT FFT of length 8192 (bit-reverse permute + 13 stages).
// tw table = exp(-2*pi*i*j/8192), j < 4096. inv=true conjugates + caller scales.
// ---------------------------------------------------------------------------
__device__ inline void init_tw(float* twr, float* twi) {
  for (int j = threadIdx.x; j < NFFT / 2; j += blockDim.x) {
    float a = -6.28318530717958647692f * (float)j / (float)NFFT;
    float s, c;
    sincosf(a, &s, &c);
    twr[j] = c;
    twi[j] = s;
  }
}

__device__ inline void fft8192(float* re, float* im, const float* twr,
                               const float* twi, bool inv) {
  const int tid = threadIdx.x;
  // in-place bit-reversal permutation
  for (int n = tid; n < NFFT; n += 256) {
    int r = __brev((unsigned)n) >> (32 - LOG2N);
    if (r > n) {
      float tr = re[n]; re[n] = re[r]; re[r] = tr;
      float ti = im[n]; im[n] = im[r]; im[r] = ti;
    }
  }
  __syncthreads();
  for (int s = 0; s < LOG2N; ++s) {
    const int m = 1 << s;
    for (int t = tid; t < NFFT / 2; t += 256) {
      const int j = t & (m - 1);
      const int pos0 = ((t >> s) << (s + 1)) + j;
      const int pos1 = pos0 + m;
      const int ti = j << (LOG2N - 1 - s);
      float wr = twr[ti];
      float wi = inv ? -twi[ti] : twi[ti];
      const float xr = re[pos1], xi = im[pos1];
      const float vr = xr * wr - xi * wi;
      const float vi = xr * wi + xi * wr;
      const float ur = re[pos0], ui = im[pos0];
      re[pos0] = ur + vr; im[pos0] = ui + vi;
      re[pos1] = ur - vr; im[pos1] = ui - vi;
    }
    __syncthreads();
  }
}

// ---------------------------------------------------------------------------
// Step 2: per (b,h,d) row: Z = FFT(q + i k); extract Qf, Kf; accumulate
// Qf*conj(Kf) into scores spectrum via atomics.
// ---------------------------------------------------------------------------
__global__ __launch_bounds__(256) void qk_scores(const float* __restrict__ Qt,
                                                 const float* __restrict__ Kt,
                                                 float* __restrict__ sfft)
{
  __shared__ float s_re[NFFT], s_im[NFFT];
  __shared__ float s_twr[NFFT / 2], s_twi[NFFT / 2];
  const int blk = blockIdx.x;            // row index: b*1024 + h*64 + d
  const long long base = (long long)blk * NFFT;
  const int bh = blk >> 6;
  const int tid = threadIdx.x;
  init_tw(s_twr, s_twi);
  for (int n = tid; n < NFFT; n += 256) {
    s_re[n] = Qt[base + n];
    s_im[n] = Kt[base + n];
  }
  __syncthreads();
  fft8192(s_re, s_im, s_twr, s_twi, false);
  float* outp = sfft + (long long)bh * NFFT * 2;
  for (int f = tid; f < NFFT; f += 256) {
    const int mf = (NFFT - f) & (NFFT - 1);
    const float zr = s_re[f], zi = s_im[f];
    const float yr = s_re[mf], yi = s_im[mf];
    const float qr = 0.5f * (zr + yr), qi = 0.5f * (zi - yi);
    const float kr = 0.5f * (zi + yi), ki = -0.5f * (zr - yr);
    const float pr = qr * kr + qi * ki;   // Qf * conj(Kf)
    const float pi = qi * kr - qr * ki;
    atomicAdd(outp + 2 * f, pr);
    atomicAdd(outp + 2 * f + 1, pi);
  }
}

// ---------------------------------------------------------------------------
// Step 3: per (b,h): scores = iFFT(sfft)*scale; softmax; attnF = FFT(attn)
// ---------------------------------------------------------------------------
__global__ __launch_bounds__(256) void softmax_attn(const float* __restrict__ sfft,
                                                    float* __restrict__ attnF)
{
  __shared__ float s_re[NFFT], s_im[NFFT];
  __shared__ float s_twr[NFFT / 2], s_twi[NFFT / 2];
  __shared__ float red[8];
  const int bh = blockIdx.x;
  const int tid = threadIdx.x;
  const float2* S = (const float2*)(sfft + (long long)bh * NFFT * 2);
  init_tw(s_twr, s_twi);
  for (int f = tid; f < NFFT; f += 256) {
    float2 z = S[f];
    s_re[f] = z.x;
    s_im[f] = z.y;
  }
  __syncthreads();
  fft8192(s_re, s_im, s_twr, s_twi, true);
  const float cs = (1.0f / (float)NFFT) * 0.125f;  // 1/N * 1/sqrt(64)
  float lmax = -1e30f;
  for (int n = tid; n < NFFT; n += 256) {
    float v = s_re[n] * cs;
    s_re[n] = v;
    lmax = fmaxf(lmax, v);
  }
  for (int o = 32; o > 0; o >>= 1) lmax = fmaxf(lmax, __shfl_down(lmax, o, 64));
  if ((tid & 63) == 0) red[tid >> 6] = lmax;
  __syncthreads();
  const float m = fmaxf(fmaxf(red[0], red[1]), fmaxf(red[2], red[3]));
  float lsum = 0.f;
  for (int n = tid; n < NFFT; n += 256) {
    float e = expf(s_re[n] - m);
    s_re[n] = e;
    lsum += e;
  }
  for (int o = 32; o > 0; o >>= 1) lsum += __shfl_down(lsum, o, 64);
  if ((tid & 63) == 0) red[4 + (tid >> 6)] = lsum;
  __syncthreads();
  const float inv = 1.0f / (red[4] + red[5] + red[6] + red[7]);
  for (int n = tid; n < NFFT; n += 256) {
    s_re[n] *= inv;
    s_im[n] = 0.f;
  }
  __syncthreads();
  fft8192(s_re, s_im, s_twr, s_twi, false);
  float2* AF = (float2*)(attnF + (long long)bh * NFFT * 2);
  for (int f = tid; f < NFFT; f += 256) AF[f] = make_float2(s_re[f], s_im[f]);
}

// ---------------------------------------------------------------------------
// Step 4: per (b,h,dpair): Z = FFT(v0 + i v1); Z *= attnF; z = iFFT(Z);
// out_d0 = Re(z), out_d1 = Im(z). (attnF conj-symmetric => both real.)
// ---------------------------------------------------------------------------
__global__ __launch_bounds__(256) void pv_out(const float* __restrict__ Vt,
                                              const float* __restrict__ attnF,
                                              float* __restrict__ Ot)
{
  __shared__ float s_re[NFFT], s_im[NFFT];
  __shared__ float s_twr[NFFT / 2], s_twi[NFFT / 2];
  const int blk = blockIdx.x;                // 0..1023 (pair of rows)
  const long long base0 = (long long)blk * 2 * NFFT;
  const long long base1 = base0 + NFFT;
  const int bh = blk >> 5;                   // (blk*2)>>6
  const int tid = threadIdx.x;
  init_tw(s_twr, s_twi);
  for (int n = tid; n < NFFT; n += 256) {
    s_re[n] = Vt[base0 + n];
    s_im[n] = Vt[base1 + n];
  }
  __syncthreads();
  fft8192(s_re, s_im, s_twr, s_twi, false);
  const float2* AF = (const float2*)(attnF + (long long)bh * NFFT * 2);
  for (int f = tid; f < NFFT; f += 256) {
    float2 a = AF[f];
    const float zr = s_re[f], zi = s_im[f];
    s_re[f] = a.x * zr - a.y * zi;
    s_im[f] = a.x * zi + a.y * zr;
  }
  __syncthreads();
  fft8192(s_re, s_im, s_twr, s_twi, true);
  const float s = 1.0f / (float)NFFT;
  for (int n = tid; n < NFFT; n += 256) {
    Ot[base0 + n] = s_re[n] * s;
    Ot[base1 + n] = s_im[n] * s;
  }
}

// ---------------------------------------------------------------------------
extern "C" void kernel_launch(void* const* d_in, const int* in_sizes, int n_in,
                              void* d_out, int out_size, void* d_ws, size_t ws_size,
                              hipStream_t stream) {
  const float* x  = (const float*)d_in[0];
  const float* Wq = (const float*)d_in[1];
  const float* bq = (const float*)d_in[2];
  const float* Wk = (const float*)d_in[3];
  const float* bk = (const float*)d_in[4];
  const float* Wv = (const float*)d_in[5];
  const float* bv = (const float*)d_in[6];
  const float* Wo = (const float*)d_in[7];
  const float* bo = (const float*)d_in[8];
  float* out = (float*)d_out;
  float* ws = (float*)d_ws;

  const long long TSZ = (long long)2 * DMODEL * NSEQ;  // 16,777,216 floats
  float* Qt = ws;                 // (b,e,n) transposed Q; later reused as Ot
  float* Kt = Qt + TSZ;
  float* sfft  = Kt + TSZ;        // 32 * 8192 complex
  float* attnF = sfft + (long long)32 * NFFT * 2;
  float* Vt = out;                // use d_out as V scratch (read before final GEMM writes)
  float* Ot = Qt;                 // reuse Q buffer for O (transposed)

  hipMemsetAsync(sfft, 0, (size_t)32 * NFFT * 2 * sizeof(float), stream);

  const dim3 blk(256);
  const long long xBS = (long long)NSEQ * DMODEL;
  const long long tBS = (long long)DMODEL * NSEQ;

  // Projections: C[e][n] = sum_d W[e][d] * x[b][n][d]   (grid: c=n tiles, r=e tiles)
  const dim3 gproj(NSEQ / 64, DMODEL / 64, 2);
  hipLaunchKernelGGL(gemm_rr, gproj, blk, 0, stream,
                     Wq, x, bq, Qt, DMODEL, DMODEL, NSEQ, 0LL, xBS, tBS, 1, 0);
  hipLaunchKernelGGL(gemm_rr, gproj, blk, 0, stream,
                     Wk, x, bk, Kt, DMODEL, DMODEL, NSEQ, 0LL, xBS, tBS, 1, 0);
  hipLaunchKernelGGL(gemm_rr, gproj, blk, 0, stream,
                     Wv, x, bv, Vt, DMODEL, DMODEL, NSEQ, 0LL, xBS, tBS, 1, 0);

  hipLaunchKernelGGL(qk_scores, dim3(2048), blk, 0, stream, Qt, Kt, sfft);
  hipLaunchKernelGGL(softmax_attn, dim3(32), blk, 0, stream, sfft, attnF);
  hipLaunchKernelGGL(pv_out, dim3(1024), blk, 0, stream, Vt, attnF, Ot);

  // Final: out[b][n][e] = sum_d Ot[b][d][n] * Wo[e][d] + bo[e]
  const dim3 gfin(DMODEL / 64, NSEQ / 64, 2);
  hipLaunchKernelGGL(gemm_rr, gfin, blk, 0, stream,
                     Ot, Wo, bo, out, NSEQ, DMODEL, DMODEL, tBS, 0LL, xBS, 2, 1);
}

// Round 2
// 1183.303 us; speedup vs baseline: 2.5345x; 2.5345x over previous
//
#include <hip/hip_runtime.h>
#include <math.h>

#define NFFT 8192
#define LOG2N 13
constexpr int DMODEL = 1024;
constexpr int NSEQ = 8192;

typedef unsigned short u16;
typedef __attribute__((ext_vector_type(8))) short bf16x8;
typedef __attribute__((ext_vector_type(4))) float f32x4;

#define GAS __attribute__((address_space(1)))
#define LAS __attribute__((address_space(3)))

__device__ inline u16 f2bf(float f) {
  unsigned u = __float_as_uint(f);
  u += 0x7fffu + ((u >> 16) & 1u);
  return (u16)(u >> 16);
}
__device__ inline float bf2f(u16 h) { return __uint_as_float(((unsigned)h) << 16); }

__device__ inline void gload_lds16(const void* g, void* l) {
  __builtin_amdgcn_global_load_lds((GAS void*)(void*)g, (LAS void*)l, 16, 0, 0);
}

// ---------------------------------------------------------------------------
// Stage a [128][64] bf16 tile (16KB) from row-major global into LDS via
// global_load_lds. LDS layout: linear 128B rows; swizzled meaning:
// slot (r, c16) holds global element-col16 (c16 ^ (r&7)).  (pre-swizzled src)
// ---------------------------------------------------------------------------
__device__ inline void stage_bf16_tile(const u16* __restrict__ g, long long strideElems,
                                       u16* lds, int tid) {
  const int w = tid >> 6;
#pragma unroll
  for (int i = 0; i < 4; ++i) {
    const int r = i * 32 + (tid >> 3);
    const int cg = ((tid & 7) ^ ((tid >> 3) & 7)) * 8;  // element col in global
    const u16* gp = g + (long long)r * strideElems + cg;
    u16* lp = lds + i * 2048 + w * 512;  // wave-uniform base (elems)
    gload_lds16(gp, lp);
  }
}

// ---------------------------------------------------------------------------
// Stage a [128][64] f32 tile, splitting to bf16 hi/lo, swizzled ds_write.
// ---------------------------------------------------------------------------
__device__ inline void stage_f32_split(const float* __restrict__ g, long long strideElems,
                                       u16* sh, u16* sl, int tid) {
#pragma unroll
  for (int p = 0; p < 8; ++p) {
    const int q = p * 256 + tid;
    const int r = q >> 4;
    const int c = (q & 15) * 4;  // f32 col 0..60
    const float4 v = *(const float4*)(g + (long long)r * strideElems + c);
    const u16 h0 = f2bf(v.x), h1 = f2bf(v.y), h2 = f2bf(v.z), h3 = f2bf(v.w);
    const u16 l0 = f2bf(v.x - bf2f(h0)), l1 = f2bf(v.y - bf2f(h1));
    const u16 l2 = f2bf(v.z - bf2f(h2)), l3 = f2bf(v.w - bf2f(h3));
    uint2 hv, lv;
    hv.x = (unsigned)h0 | ((unsigned)h1 << 16); hv.y = (unsigned)h2 | ((unsigned)h3 << 16);
    lv.x = (unsigned)l0 | ((unsigned)l1 << 16); lv.y = (unsigned)l2 | ((unsigned)l3 << 16);
    const int byteoff = r * 128 + ((((c >> 3) ^ (r & 7)) << 4)) + ((c & 4) << 1);
    *(uint2*)((char*)sh + byteoff) = hv;
    *(uint2*)((char*)sl + byteoff) = lv;
  }
}

__device__ inline bf16x8 frag_ld(const u16* s, int row, int c16) {
  return *(const bf16x8*)(s + row * 64 + ((c16 ^ (row & 7)) << 3));
}

// ---------------------------------------------------------------------------
// Split-bf16 MFMA GEMM: C[m][n] = sum_k A[m][k]*B[n][k] (+bias)
// A given as bf16 hi/lo pair (global, k-contig). B either bf16 pair (BF32=0)
// or fp32 (BF32=1, split on the fly). 128x128 tile, BK=64, 4 waves.
// ---------------------------------------------------------------------------
template <int BF32>
__global__ __launch_bounds__(256, 2) void gemm_sp(
    const u16* __restrict__ Ah, const u16* __restrict__ Al, long long aStride, long long aBS,
    const void* __restrict__ B0, const void* __restrict__ B1, long long bStride, long long bBS,
    const float* __restrict__ bias, int biasMode,
    float* __restrict__ C, long long ldc, long long cBS, int K)
{
  __shared__ __align__(16) u16 sAh[128 * 64];
  __shared__ __align__(16) u16 sAl[128 * 64];
  __shared__ __align__(16) u16 sBh[128 * 64];
  __shared__ __align__(16) u16 sBl[128 * 64];
  const int tid = threadIdx.x;
  const int bx = blockIdx.x, by = blockIdx.y, bz = blockIdx.z;
  const int m0 = by * 128, n0 = bx * 128;
  const u16* ahg = Ah + (long long)bz * aBS + (long long)m0 * aStride;
  const u16* alg = Al + (long long)bz * aBS + (long long)m0 * aStride;
  const u16* bhg = (const u16*)B0 + (long long)bz * bBS + (long long)n0 * bStride;
  const u16* blg = (const u16*)B1 + (long long)bz * bBS + (long long)n0 * bStride;
  const float* bfg = (const float*)B0 + (long long)bz * bBS + (long long)n0 * bStride;

  const int w = tid >> 6, lane = tid & 63, lr = lane & 15, lk = lane >> 4;
  const int wm = w >> 1, wn = w & 1;

  f32x4 acc[4][4];
#pragma unroll
  for (int i = 0; i < 4; ++i)
#pragma unroll
    for (int j = 0; j < 4; ++j) acc[i][j] = {0.f, 0.f, 0.f, 0.f};

  for (int k0 = 0; k0 < K; k0 += 64) {
    stage_bf16_tile(ahg + k0, aStride, sAh, tid);
    stage_bf16_tile(alg + k0, aStride, sAl, tid);
    if (BF32) {
      stage_f32_split(bfg + k0, bStride, sBh, sBl, tid);
    } else {
      stage_bf16_tile(bhg + k0, bStride, sBh, tid);
      stage_bf16_tile(blg + k0, bStride, sBl, tid);
    }
    __syncthreads();
#pragma unroll
    for (int kk = 0; kk < 2; ++kk) {
      bf16x8 fah[4], fal[4], fbh[4], fbl[4];
#pragma unroll
      for (int i = 0; i < 4; ++i) {
        const int ar = wm * 64 + i * 16 + lr;
        const int br = wn * 64 + i * 16 + lr;
        const int c16 = kk * 4 + lk;
        fah[i] = frag_ld(sAh, ar, c16);
        fal[i] = frag_ld(sAl, ar, c16);
        fbh[i] = frag_ld(sBh, br, c16);
        fbl[i] = frag_ld(sBl, br, c16);
      }
#pragma unroll
      for (int i = 0; i < 4; ++i)
#pragma unroll
        for (int j = 0; j < 4; ++j) {
          acc[i][j] = __builtin_amdgcn_mfma_f32_16x16x32_bf16(fah[i], fbh[j], acc[i][j], 0, 0, 0);
          acc[i][j] = __builtin_amdgcn_mfma_f32_16x16x32_bf16(fah[i], fbl[j], acc[i][j], 0, 0, 0);
          acc[i][j] = __builtin_amdgcn_mfma_f32_16x16x32_bf16(fal[i], fbh[j], acc[i][j], 0, 0, 0);
        }
    }
    __syncthreads();
  }

  float* Cb = C + (long long)bz * cBS;
#pragma unroll
  for (int i = 0; i < 4; ++i) {
    const int rbase = m0 + wm * 64 + i * 16 + lk * 4;
#pragma unroll
    for (int j = 0; j < 4; ++j) {
      const int cc = n0 + wn * 64 + j * 16 + lr;
      const float bc = (biasMode == 2) ? bias[cc] : 0.f;
#pragma unroll
      for (int rr = 0; rr < 4; ++rr) {
        const float br_ = (biasMode == 1) ? bias[rbase + rr] : bc;
        Cb[(long long)(rbase + rr) * ldc + cc] = acc[i][j][rr] + br_;
      }
    }
  }
}

// ---------------------------------------------------------------------------
// Converters
// ---------------------------------------------------------------------------
__global__ __launch_bounds__(256) void split_f32(const float* __restrict__ in,
                                                 u16* __restrict__ h, u16* __restrict__ l,
                                                 int n4) {
  const int i = blockIdx.x * 256 + threadIdx.x;
  if (i >= n4) return;
  const float4 v = ((const float4*)in)[i];
  const u16 h0 = f2bf(v.x), h1 = f2bf(v.y), h2 = f2bf(v.z), h3 = f2bf(v.w);
  const u16 l0 = f2bf(v.x - bf2f(h0)), l1 = f2bf(v.y - bf2f(h1));
  const u16 l2 = f2bf(v.z - bf2f(h2)), l3 = f2bf(v.w - bf2f(h3));
  uint2 hv, lv;
  hv.x = (unsigned)h0 | ((unsigned)h1 << 16); hv.y = (unsigned)h2 | ((unsigned)h3 << 16);
  lv.x = (unsigned)l0 | ((unsigned)l1 << 16); lv.y = (unsigned)l2 | ((unsigned)l3 << 16);
  ((uint2*)h)[i] = hv;
  ((uint2*)l)[i] = lv;
}

// Ot [2][1024 d][8192 n] f32  ->  Oh/Ol [2][8192 n][1024 d] bf16
__global__ __launch_bounds__(256) void transp_split(const float* __restrict__ in,
                                                    u16* __restrict__ h, u16* __restrict__ l) {
  __shared__ float t[64][65];
  const int bz = blockIdx.z;
  const int d0 = blockIdx.y * 64, n0 = blockIdx.x * 64;
  const float* ip = in + (long long)bz * 8388608 + (long long)d0 * NSEQ + n0;
#pragma unroll 4
  for (int i = 0; i < 16; ++i) {
    const int idx = i * 256 + threadIdx.x;
    const int r = idx >> 6, c = idx & 63;
    t[r][c] = ip[(long long)r * NSEQ + c];
  }
  __syncthreads();
#pragma unroll 4
  for (int i = 0; i < 16; ++i) {
    const int idx = i * 256 + threadIdx.x;
    const int rn = idx >> 6, cd = idx & 63;
    const float v = t[cd][rn];
    const u16 hh = f2bf(v);
    const u16 ll = f2bf(v - bf2f(hh));
    const long long o = (long long)bz * 8388608 + (long long)(n0 + rn) * 1024 + d0 + cd;
    h[o] = hh;
    l[o] = ll;
  }
}

__global__ __launch_bounds__(256) void tw_init(float2* __restrict__ tw) {
  const int j = blockIdx.x * 256 + threadIdx.x;
  if (j >= NFFT / 2) return;
  const float a = -6.28318530717958647692f * (float)j / (float)NFFT;
  float s, c;
  sincosf(a, &s, &c);
  tw[j] = make_float2(c, s);
}

// ---------------------------------------------------------------------------
// In-LDS radix-2 FFT, twiddles from global (L1-resident 32KB table).
// ---------------------------------------------------------------------------
__device__ inline void fft8192g(float* re, float* im, const float2* __restrict__ tw, bool inv) {
  const int tid = threadIdx.x;
  for (int n = tid; n < NFFT; n += 256) {
    const int r = __brev((unsigned)n) >> (32 - LOG2N);
    if (r > n) {
      float tr = re[n]; re[n] = re[r]; re[r] = tr;
      float ti = im[n]; im[n] = im[r]; im[r] = ti;
    }
  }
  __syncthreads();
  for (int s = 0; s < LOG2N; ++s) {
    const int m = 1 << s;
    for (int t = tid; t < NFFT / 2; t += 256) {
      const int j = t & (m - 1);
      const int p0 = ((t >> s) << (s + 1)) + j;
      const int p1 = p0 + m;
      const float2 w = tw[j << (LOG2N - 1 - s)];
      const float wr = w.x;
      const float wi = inv ? -w.y : w.y;
      const float xr = re[p1], xi = im[p1];
      const float vr = xr * wr - xi * wi;
      const float vi = xr * wi + xi * wr;
      const float ur = re[p0], ui = im[p0];
      re[p0] = ur + vr; im[p0] = ui + vi;
      re[p1] = ur - vr; im[p1] = ui - vi;
    }
    __syncthreads();
  }
}

// ---------------------------------------------------------------------------
// qk_scores: 4 d-channels per block; register-accumulated Qf*conj(Kf);
// one atomic pass per block.
// ---------------------------------------------------------------------------
__global__ __launch_bounds__(256) void qk_scores(const float* __restrict__ Qt,
                                                 const float* __restrict__ Kt,
                                                 const float2* __restrict__ tw,
                                                 float* __restrict__ sfft) {
  __shared__ float s_re[NFFT], s_im[NFFT];
  const int blk = blockIdx.x;  // 512
  const int bh = blk >> 4;
  const int d0 = (blk & 15) * 4;
  const int tid = threadIdx.x;
  float2 racc[32];
#pragma unroll
  for (int j = 0; j < 32; ++j) racc[j] = make_float2(0.f, 0.f);

  for (int ch = 0; ch < 4; ++ch) {
    const long long base = ((long long)bh * 64 + d0 + ch) * NFFT;
    if (ch) __syncthreads();  // protect prior unpack reads
    for (int n = tid; n < NFFT; n += 256) {
      s_re[n] = Qt[base + n];
      s_im[n] = Kt[base + n];
    }
    __syncthreads();
    fft8192g(s_re, s_im, tw, false);
#pragma unroll
    for (int j = 0; j < 32; ++j) {
      const int f = j * 256 + tid;
      const int mf = (NFFT - f) & (NFFT - 1);
      const float zr = s_re[f], zi = s_im[f];
      const float yr = s_re[mf], yi = s_im[mf];
      const float qr = 0.5f * (zr + yr), qi = 0.5f * (zi - yi);
      const float kr = 0.5f * (zi + yi), ki = -0.5f * (zr - yr);
      racc[j].x += qr * kr + qi * ki;
      racc[j].y += qi * kr - qr * ki;
    }
  }
  float* outp = sfft + (long long)bh * NFFT * 2;
#pragma unroll
  for (int j = 0; j < 32; ++j) {
    const int f = j * 256 + tid;
    atomicAdd(outp + 2 * f, racc[j].x);
    atomicAdd(outp + 2 * f + 1, racc[j].y);
  }
}

// ---------------------------------------------------------------------------
__global__ __launch_bounds__(256) void softmax_attn(const float* __restrict__ sfft,
                                                    const float2* __restrict__ tw,
                                                    float* __restrict__ attnF) {
  __shared__ float s_re[NFFT], s_im[NFFT];
  __shared__ float red[8];
  const int bh = blockIdx.x;
  const int tid = threadIdx.x;
  const float2* S = (const float2*)(sfft + (long long)bh * NFFT * 2);
  for (int f = tid; f < NFFT; f += 256) {
    const float2 z = S[f];
    s_re[f] = z.x;
    s_im[f] = z.y;
  }
  __syncthreads();
  fft8192g(s_re, s_im, tw, true);
  const float cs = (1.0f / (float)NFFT) * 0.125f;  // 1/N * 1/sqrt(64)
  float lmax = -1e30f;
  for (int n = tid; n < NFFT; n += 256) {
    const float v = s_re[n] * cs;
    s_re[n] = v;
    lmax = fmaxf(lmax, v);
  }
  for (int o = 32; o > 0; o >>= 1) lmax = fmaxf(lmax, __shfl_down(lmax, o, 64));
  if ((tid & 63) == 0) red[tid >> 6] = lmax;
  __syncthreads();
  const float m = fmaxf(fmaxf(red[0], red[1]), fmaxf(red[2], red[3]));
  float lsum = 0.f;
  for (int n = tid; n < NFFT; n += 256) {
    const float e = expf(s_re[n] - m);
    s_re[n] = e;
    lsum += e;
  }
  for (int o = 32; o > 0; o >>= 1) lsum += __shfl_down(lsum, o, 64);
  if ((tid & 63) == 0) red[4 + (tid >> 6)] = lsum;
  __syncthreads();
  const float inv = 1.0f / (red[4] + red[5] + red[6] + red[7]);
  for (int n = tid; n < NFFT; n += 256) {
    s_re[n] *= inv;
    s_im[n] = 0.f;
  }
  __syncthreads();
  fft8192g(s_re, s_im, tw, false);
  float2* AF = (float2*)(attnF + (long long)bh * NFFT * 2);
  for (int f = tid; f < NFFT; f += 256) AF[f] = make_float2(s_re[f], s_im[f]);
}

// ---------------------------------------------------------------------------
__global__ __launch_bounds__(256) void pv_out(const float* __restrict__ Vt,
                                              const float* __restrict__ attnF,
                                              const float2* __restrict__ tw,
                                              float* __restrict__ Ot) {
  __shared__ float s_re[NFFT], s_im[NFFT];
  const int blk = blockIdx.x;  // 1024 (d-pair)
  const long long base0 = (long long)blk * 2 * NFFT;
  const long long base1 = base0 + NFFT;
  const int bh = blk >> 5;
  const int tid = threadIdx.x;
  for (int n = tid; n < NFFT; n += 256) {
    s_re[n] = Vt[base0 + n];
    s_im[n] = Vt[base1 + n];
  }
  __syncthreads();
  fft8192g(s_re, s_im, tw, false);
  const float2* AF = (const float2*)(attnF + (long long)bh * NFFT * 2);
  for (int f = tid; f < NFFT; f += 256) {
    const float2 a = AF[f];
    const float zr = s_re[f], zi = s_im[f];
    s_re[f] = a.x * zr - a.y * zi;
    s_im[f] = a.x * zi + a.y * zr;
  }
  __syncthreads();
  fft8192g(s_re, s_im, tw, true);
  const float s = 1.0f / (float)NFFT;
  for (int n = tid; n < NFFT; n += 256) {
    Ot[base0 + n] = s_re[n] * s;
    Ot[base1 + n] = s_im[n] * s;
  }
}

// ---------------------------------------------------------------------------
extern "C" void kernel_launch(void* const* d_in, const int* in_sizes, int n_in,
                              void* d_out, int out_size, void* d_ws, size_t ws_size,
                              hipStream_t stream) {
  const float* x  = (const float*)d_in[0];
  const float* Wq = (const float*)d_in[1];
  const float* bq = (const float*)d_in[2];
  const float* Wk = (const float*)d_in[3];
  const float* bk = (const float*)d_in[4];
  const float* Wv = (const float*)d_in[5];
  const float* bv = (const float*)d_in[6];
  const float* Wo = (const float*)d_in[7];
  const float* bo = (const float*)d_in[8];
  float* out = (float*)d_out;
  float* ws = (float*)d_ws;

  const long long TSZ = (long long)2 * DMODEL * NSEQ;  // 16,777,216 floats
  float* Qt = ws;
  float* Kt = Qt + TSZ;
  float* sfft = Kt + TSZ;                       // 32*8192 complex
  float* attnF = sfft + (long long)32 * NFFT * 2;
  float2* tw = (float2*)(attnF + (long long)32 * NFFT * 2);   // 4096 float2
  u16* Wsp = (u16*)(tw + NFFT / 2);             // 8 x 1Mi u16
  const long long WSZ = (long long)DMODEL * DMODEL;
  u16* Wqh = Wsp + 0 * WSZ; u16* Wql = Wsp + 1 * WSZ;
  u16* Wkh = Wsp + 2 * WSZ; u16* Wkl = Wsp + 3 * WSZ;
  u16* Wvh = Wsp + 4 * WSZ; u16* Wvl = Wsp + 5 * WSZ;
  u16* Woh = Wsp + 6 * WSZ; u16* Wol = Wsp + 7 * WSZ;
  float* Vt = out;            // d_out as V scratch
  float* Ot = Qt;             // reuse Q buffer for O (transposed)
  u16* Oh = (u16*)Kt;         // reuse K buffer for split-O
  u16* Ol = Oh + TSZ;

  const dim3 blk(256);
  const int w4 = (int)(WSZ / 4);
  hipLaunchKernelGGL(split_f32, dim3(w4 / 256), blk, 0, stream, Wq, Wqh, Wql, w4);
  hipLaunchKernelGGL(split_f32, dim3(w4 / 256), blk, 0, stream, Wk, Wkh, Wkl, w4);
  hipLaunchKernelGGL(split_f32, dim3(w4 / 256), blk, 0, stream, Wv, Wvh, Wvl, w4);
  hipLaunchKernelGGL(split_f32, dim3(w4 / 256), blk, 0, stream, Wo, Woh, Wol, w4);
  hipLaunchKernelGGL(tw_init, dim3(16), blk, 0, stream, tw);
  hipMemsetAsync(sfft, 0, (size_t)32 * NFFT * 2 * sizeof(float), stream);

  const long long xBS = (long long)NSEQ * DMODEL;
  const long long tBS = (long long)DMODEL * NSEQ;

  // Projections: C[e][n] = sum_d W[e][d] * x[b][n][d]
  const dim3 gp(NSEQ / 128, DMODEL / 128, 2);
  hipLaunchKernelGGL((gemm_sp<1>), gp, blk, 0, stream,
                     Wqh, Wql, (long long)DMODEL, 0LL, (const void*)x, (const void*)nullptr,
                     (long long)DMODEL, xBS, bq, 1, Qt, (long long)NSEQ, tBS, DMODEL);
  hipLaunchKernelGGL((gemm_sp<1>), gp, blk, 0, stream,
                     Wkh, Wkl, (long long)DMODEL, 0LL, (const void*)x, (const void*)nullptr,
                     (long long)DMODEL, xBS, bk, 1, Kt, (long long)NSEQ, tBS, DMODEL);
  hipLaunchKernelGGL((gemm_sp<1>), gp, blk, 0, stream,
                     Wvh, Wvl, (long long)DMODEL, 0LL, (const void*)x, (const void*)nullptr,
                     (long long)DMODEL, xBS, bv, 1, Vt, (long long)NSEQ, tBS, DMODEL);

  hipLaunchKernelGGL(qk_scores, dim3(512), blk, 0, stream, Qt, Kt, tw, sfft);
  hipLaunchKernelGGL(softmax_attn, dim3(32), blk, 0, stream, sfft, tw, attnF);
  hipLaunchKernelGGL(pv_out, dim3(1024), blk, 0, stream, Vt, attnF, tw, Ot);

  hipLaunchKernelGGL(transp_split, dim3(NSEQ / 64, DMODEL / 64, 2), blk, 0, stream, Ot, Oh, Ol);

  // Final: out[b][n][e] = sum_d O[b][n][d] * Wo[e][d] + bo[e]
  const dim3 gf(DMODEL / 128, NSEQ / 128, 2);
  hipLaunchKernelGGL((gemm_sp<0>), gf, blk, 0, stream,
                     Oh, Ol, (long long)DMODEL, tBS, (const void*)Woh, (const void*)Wol,
                     (long long)DMODEL, 0LL, bo, 2, out, (long long)DMODEL, xBS, DMODEL);
}

// Round 4
// 927.753 us; speedup vs baseline: 3.2326x; 1.2755x over previous
//
#include <hip/hip_runtime.h>
#include <math.h>

#define NFFT 8192
#define LOG2N 13
constexpr int DMODEL = 1024;
constexpr int NSEQ = 8192;

typedef unsigned short u16;
typedef __attribute__((ext_vector_type(8))) short bf16x8;
typedef __attribute__((ext_vector_type(4))) float f32x4;

#define GAS __attribute__((address_space(1)))
#define LAS __attribute__((address_space(3)))
#define SW(i) ((i) ^ (((i) >> 5) & 31))

__device__ inline u16 f2bf(float f) {
  unsigned u = __float_as_uint(f);
  u += 0x7fffu + ((u >> 16) & 1u);
  return (u16)(u >> 16);
}
__device__ inline float bf2f(u16 h) { return __uint_as_float(((unsigned)h) << 16); }

__device__ inline void gload_lds16(const void* g, void* l) {
  __builtin_amdgcn_global_load_lds((GAS void*)(void*)g, (LAS void*)l, 16, 0, 0);
}

// ===========================================================================
// GEMM machinery (unchanged from round 2 — verified passing)
// ===========================================================================
__device__ inline void stage_bf16_tile(const u16* __restrict__ g, long long strideElems,
                                       u16* lds, int tid) {
  const int w = tid >> 6;
#pragma unroll
  for (int i = 0; i < 4; ++i) {
    const int r = i * 32 + (tid >> 3);
    const int cg = ((tid & 7) ^ ((tid >> 3) & 7)) * 8;
    const u16* gp = g + (long long)r * strideElems + cg;
    u16* lp = lds + i * 2048 + w * 512;
    gload_lds16(gp, lp);
  }
}

__device__ inline void stage_f32_split(const float* __restrict__ g, long long strideElems,
                                       u16* sh, u16* sl, int tid) {
#pragma unroll
  for (int p = 0; p < 8; ++p) {
    const int q = p * 256 + tid;
    const int r = q >> 4;
    const int c = (q & 15) * 4;
    const float4 v = *(const float4*)(g + (long long)r * strideElems + c);
    const u16 h0 = f2bf(v.x), h1 = f2bf(v.y), h2 = f2bf(v.z), h3 = f2bf(v.w);
    const u16 l0 = f2bf(v.x - bf2f(h0)), l1 = f2bf(v.y - bf2f(h1));
    const u16 l2 = f2bf(v.z - bf2f(h2)), l3 = f2bf(v.w - bf2f(h3));
    uint2 hv, lv;
    hv.x = (unsigned)h0 | ((unsigned)h1 << 16); hv.y = (unsigned)h2 | ((unsigned)h3 << 16);
    lv.x = (unsigned)l0 | ((unsigned)l1 << 16); lv.y = (unsigned)l2 | ((unsigned)l3 << 16);
    const int byteoff = r * 128 + ((((c >> 3) ^ (r & 7)) << 4)) + ((c & 4) << 1);
    *(uint2*)((char*)sh + byteoff) = hv;
    *(uint2*)((char*)sl + byteoff) = lv;
  }
}

__device__ inline bf16x8 frag_ld(const u16* s, int row, int c16) {
  return *(const bf16x8*)(s + row * 64 + ((c16 ^ (row & 7)) << 3));
}

template <int BF32>
__global__ __launch_bounds__(256, 2) void gemm_sp(
    const u16* __restrict__ Ah, const u16* __restrict__ Al, long long aStride, long long aBS,
    const void* __restrict__ B0, const void* __restrict__ B1, long long bStride, long long bBS,
    const float* __restrict__ bias, int biasMode,
    float* __restrict__ C, long long ldc, long long cBS, int K)
{
  __shared__ __align__(16) u16 sAh[128 * 64];
  __shared__ __align__(16) u16 sAl[128 * 64];
  __shared__ __align__(16) u16 sBh[128 * 64];
  __shared__ __align__(16) u16 sBl[128 * 64];
  const int tid = threadIdx.x;
  const int bx = blockIdx.x, by = blockIdx.y, bz = blockIdx.z;
  const int m0 = by * 128, n0 = bx * 128;
  const u16* ahg = Ah + (long long)bz * aBS + (long long)m0 * aStride;
  const u16* alg = Al + (long long)bz * aBS + (long long)m0 * aStride;
  const u16* bhg = (const u16*)B0 + (long long)bz * bBS + (long long)n0 * bStride;
  const u16* blg = (const u16*)B1 + (long long)bz * bBS + (long long)n0 * bStride;
  const float* bfg = (const float*)B0 + (long long)bz * bBS + (long long)n0 * bStride;

  const int w = tid >> 6, lane = tid & 63, lr = lane & 15, lk = lane >> 4;
  const int wm = w >> 1, wn = w & 1;

  f32x4 acc[4][4];
#pragma unroll
  for (int i = 0; i < 4; ++i)
#pragma unroll
    for (int j = 0; j < 4; ++j) acc[i][j] = {0.f, 0.f, 0.f, 0.f};

  for (int k0 = 0; k0 < K; k0 += 64) {
    stage_bf16_tile(ahg + k0, aStride, sAh, tid);
    stage_bf16_tile(alg + k0, aStride, sAl, tid);
    if (BF32) {
      stage_f32_split(bfg + k0, bStride, sBh, sBl, tid);
    } else {
      stage_bf16_tile(bhg + k0, bStride, sBh, tid);
      stage_bf16_tile(blg + k0, bStride, sBl, tid);
    }
    __syncthreads();
#pragma unroll
    for (int kk = 0; kk < 2; ++kk) {
      bf16x8 fah[4], fal[4], fbh[4], fbl[4];
#pragma unroll
      for (int i = 0; i < 4; ++i) {
        const int ar = wm * 64 + i * 16 + lr;
        const int br = wn * 64 + i * 16 + lr;
        const int c16 = kk * 4 + lk;
        fah[i] = frag_ld(sAh, ar, c16);
        fal[i] = frag_ld(sAl, ar, c16);
        fbh[i] = frag_ld(sBh, br, c16);
        fbl[i] = frag_ld(sBl, br, c16);
      }
#pragma unroll
      for (int i = 0; i < 4; ++i)
#pragma unroll
        for (int j = 0; j < 4; ++j) {
          acc[i][j] = __builtin_amdgcn_mfma_f32_16x16x32_bf16(fah[i], fbh[j], acc[i][j], 0, 0, 0);
          acc[i][j] = __builtin_amdgcn_mfma_f32_16x16x32_bf16(fah[i], fbl[j], acc[i][j], 0, 0, 0);
          acc[i][j] = __builtin_amdgcn_mfma_f32_16x16x32_bf16(fal[i], fbh[j], acc[i][j], 0, 0, 0);
        }
    }
    __syncthreads();
  }

  float* Cb = C + (long long)bz * cBS;
#pragma unroll
  for (int i = 0; i < 4; ++i) {
    const int rbase = m0 + wm * 64 + i * 16 + lk * 4;
#pragma unroll
    for (int j = 0; j < 4; ++j) {
      const int cc = n0 + wn * 64 + j * 16 + lr;
      const float bc = (biasMode == 2) ? bias[cc] : 0.f;
#pragma unroll
      for (int rr = 0; rr < 4; ++rr) {
        const float br_ = (biasMode == 1) ? bias[rbase + rr] : bc;
        Cb[(long long)(rbase + rr) * ldc + cc] = acc[i][j][rr] + br_;
      }
    }
  }
}

__global__ __launch_bounds__(256) void split_f32(const float* __restrict__ in,
                                                 u16* __restrict__ h, u16* __restrict__ l,
                                                 int n4) {
  const int i = blockIdx.x * 256 + threadIdx.x;
  if (i >= n4) return;
  const float4 v = ((const float4*)in)[i];
  const u16 h0 = f2bf(v.x), h1 = f2bf(v.y), h2 = f2bf(v.z), h3 = f2bf(v.w);
  const u16 l0 = f2bf(v.x - bf2f(h0)), l1 = f2bf(v.y - bf2f(h1));
  const u16 l2 = f2bf(v.z - bf2f(h2)), l3 = f2bf(v.w - bf2f(h3));
  uint2 hv, lv;
  hv.x = (unsigned)h0 | ((unsigned)h1 << 16); hv.y = (unsigned)h2 | ((unsigned)h3 << 16);
  lv.x = (unsigned)l0 | ((unsigned)l1 << 16); lv.y = (unsigned)l2 | ((unsigned)l3 << 16);
  ((uint2*)h)[i] = hv;
  ((uint2*)l)[i] = lv;
}

__global__ __launch_bounds__(256) void transp_split(const float* __restrict__ in,
                                                    u16* __restrict__ h, u16* __restrict__ l) {
  __shared__ float t[64][65];
  const int bz = blockIdx.z;
  const int d0 = blockIdx.y * 64, n0 = blockIdx.x * 64;
  const float* ip = in + (long long)bz * 8388608 + (long long)d0 * NSEQ + n0;
#pragma unroll 4
  for (int i = 0; i < 16; ++i) {
    const int idx = i * 256 + threadIdx.x;
    const int r = idx >> 6, c = idx & 63;
    t[r][c] = ip[(long long)r * NSEQ + c];
  }
  __syncthreads();
#pragma unroll 4
  for (int i = 0; i < 16; ++i) {
    const int idx = i * 256 + threadIdx.x;
    const int rn = idx >> 6, cd = idx & 63;
    const float v = t[cd][rn];
    const u16 hh = f2bf(v);
    const u16 ll = f2bf(v - bf2f(hh));
    const long long o = (long long)bz * 8388608 + (long long)(n0 + rn) * 1024 + d0 + cd;
    h[o] = hh;
    l[o] = ll;
  }
}

// ===========================================================================
// FFT: radix-8 DIF (natural in -> scrambled out) / radix-8 DIT (scrambled in
// -> natural out). Radix-8 stages: 1024 butterflies (k<4); radix-2 stage:
// 4096 butterflies (k<16 — the round-3 bug was k<4 here).
// Scrambled p <-> freq f: p = 1024(f&7) + 128((f>>3)&7) + 16((f>>6)&7)
//                           + 2((f>>9)&7) + (f>>12)
// ===========================================================================
__global__ __launch_bounds__(256) void tw_init(float2* __restrict__ tw) {
  const int j = blockIdx.x * 256 + threadIdx.x;
  if (j >= NFFT) return;
  const float a = -6.28318530717958647692f * (float)j / (float)NFFT;
  float s, c;
  sincosf(a, &s, &c);
  tw[j] = make_float2(c, s);
}

template <int INV>
__device__ inline void dft8(float xr[8], float xi[8]) {
  float er[4], ei[4], orr[4], oi[4];
  {
    const float s0r = xr[0] + xr[4], s0i = xi[0] + xi[4];
    const float s1r = xr[0] - xr[4], s1i = xi[0] - xi[4];
    const float s2r = xr[2] + xr[6], s2i = xi[2] + xi[6];
    const float s3r = xr[2] - xr[6], s3i = xi[2] - xi[6];
    const float t3r = INV ? -s3i : s3i;
    const float t3i = INV ? s3r : -s3r;
    er[0] = s0r + s2r; ei[0] = s0i + s2i;
    er[1] = s1r + t3r; ei[1] = s1i + t3i;
    er[2] = s0r - s2r; ei[2] = s0i - s2i;
    er[3] = s1r - t3r; ei[3] = s1i - t3i;
  }
  {
    const float s0r = xr[1] + xr[5], s0i = xi[1] + xi[5];
    const float s1r = xr[1] - xr[5], s1i = xi[1] - xi[5];
    const float s2r = xr[3] + xr[7], s2i = xi[3] + xi[7];
    const float s3r = xr[3] - xr[7], s3i = xi[3] - xi[7];
    const float t3r = INV ? -s3i : s3i;
    const float t3i = INV ? s3r : -s3r;
    orr[0] = s0r + s2r; oi[0] = s0i + s2i;
    orr[1] = s1r + t3r; oi[1] = s1i + t3i;
    orr[2] = s0r - s2r; oi[2] = s0i - s2i;
    orr[3] = s1r - t3r; oi[3] = s1i - t3i;
  }
  const float c = 0.70710678118654752440f;
  xr[0] = er[0] + orr[0]; xi[0] = ei[0] + oi[0];
  xr[4] = er[0] - orr[0]; xi[4] = ei[0] - oi[0];
  {
    const float wi = INV ? c : -c;
    const float pr = orr[1] * c - oi[1] * wi;
    const float pi = orr[1] * wi + oi[1] * c;
    xr[1] = er[1] + pr; xi[1] = ei[1] + pi;
    xr[5] = er[1] - pr; xi[5] = ei[1] - pi;
  }
  {
    const float pr = INV ? -oi[2] : oi[2];
    const float pi = INV ? orr[2] : -orr[2];
    xr[2] = er[2] + pr; xi[2] = ei[2] + pi;
    xr[6] = er[2] - pr; xi[6] = ei[2] - pi;
  }
  {
    const float wi = INV ? c : -c;
    const float pr = -orr[3] * c - oi[3] * wi;
    const float pi = orr[3] * wi - oi[3] * c;
    xr[3] = er[3] + pr; xi[3] = ei[3] + pi;
    xr[7] = er[3] - pr; xi[7] = ei[3] - pi;
  }
}

__device__ inline void bfly8_dif(float* re, float* im, const float2* __restrict__ tw,
                                 int base, int s, int j, int step) {
  float xr[8], xi[8];
  int idx[8];
#pragma unroll
  for (int q = 0; q < 8; ++q) {
    idx[q] = SW(base + q * s);
    xr[q] = re[idx[q]];
    xi[q] = im[idx[q]];
  }
  dft8<0>(xr, xi);
#pragma unroll
  for (int q = 1; q < 8; ++q) {
    const float2 w = tw[(j * q * step) & (NFFT - 1)];
    const float pr = xr[q] * w.x - xi[q] * w.y;
    const float pi = xr[q] * w.y + xi[q] * w.x;
    xr[q] = pr; xi[q] = pi;
  }
#pragma unroll
  for (int q = 0; q < 8; ++q) {
    re[idx[q]] = xr[q];
    im[idx[q]] = xi[q];
  }
}

__device__ inline void bfly8_dit(float* re, float* im, const float2* __restrict__ tw,
                                 int base, int m, int j, int step) {
  float xr[8], xi[8];
  int idx[8];
#pragma unroll
  for (int r = 0; r < 8; ++r) {
    idx[r] = SW(base + r * m);
    xr[r] = re[idx[r]];
    xi[r] = im[idx[r]];
  }
#pragma unroll
  for (int r = 1; r < 8; ++r) {
    const float2 w = tw[(j * r * step) & (NFFT - 1)];  // x * conj(w)
    const float pr = xr[r] * w.x + xi[r] * w.y;
    const float pi = xi[r] * w.x - xr[r] * w.y;
    xr[r] = pr; xi[r] = pi;
  }
  dft8<1>(xr, xi);
#pragma unroll
  for (int r = 0; r < 8; ++r) {
    re[idx[r]] = xr[r];
    im[idx[r]] = xi[r];
  }
}

__device__ inline void fft_dif(float* re, float* im, const float2* __restrict__ tw) {
  const int t = threadIdx.x;
#pragma unroll
  for (int k = 0; k < 4; ++k) {          // L=8192, s=1024
    const int j = t + 256 * k;
    bfly8_dif(re, im, tw, j, 1024, j, 1);
  }
  __syncthreads();
#pragma unroll
  for (int k = 0; k < 4; ++k) {          // L=1024, s=128
    const int u = t + 256 * k;
    const int blk = u >> 7, j = u & 127;
    bfly8_dif(re, im, tw, blk * 1024 + j, 128, j, 8);
  }
  __syncthreads();
#pragma unroll
  for (int k = 0; k < 4; ++k) {          // L=128, s=16 (special lane map)
    const int j = t & 15;
    const int blk = ((t >> 4) & 3) * 4 + (t >> 6) * 16 + k;
    bfly8_dif(re, im, tw, blk * 128 + j, 16, j, 64);
  }
  __syncthreads();
#pragma unroll
  for (int k = 0; k < 4; ++k) {          // L=16, s=2
    const int u = t + 256 * k;
    const int blk = u >> 1, j = u & 1;
    bfly8_dif(re, im, tw, blk * 16 + j, 2, j, 512);
  }
  __syncthreads();
#pragma unroll
  for (int k = 0; k < 16; ++k) {         // radix-2, L=2: 4096 butterflies!
    const int u = t + 256 * k;
    const int a = SW(2 * u), b = SW(2 * u + 1);
    const float ar = re[a], ai = im[a], br = re[b], bi = im[b];
    re[a] = ar + br; im[a] = ai + bi;
    re[b] = ar - br; im[b] = ai - bi;
  }
  __syncthreads();
}

__device__ inline void fft_dit(float* re, float* im, const float2* __restrict__ tw) {
  const int t = threadIdx.x;
#pragma unroll
  for (int k = 0; k < 16; ++k) {         // radix-2, m=1: 4096 butterflies!
    const int u = t + 256 * k;
    const int a = SW(2 * u), b = SW(2 * u + 1);
    const float ar = re[a], ai = im[a], br = re[b], bi = im[b];
    re[a] = ar + br; im[a] = ai + bi;
    re[b] = ar - br; im[b] = ai - bi;
  }
  __syncthreads();
#pragma unroll
  for (int k = 0; k < 4; ++k) {          // m=2 (L=16)
    const int u = t + 256 * k;
    const int blk = u >> 1, j = u & 1;
    bfly8_dit(re, im, tw, blk * 16 + j, 2, j, 512);
  }
  __syncthreads();
#pragma unroll
  for (int k = 0; k < 4; ++k) {          // m=16 (L=128, special lane map)
    const int j = t & 15;
    const int blk = ((t >> 4) & 3) * 4 + (t >> 6) * 16 + k;
    bfly8_dit(re, im, tw, blk * 128 + j, 16, j, 64);
  }
  __syncthreads();
#pragma unroll
  for (int k = 0; k < 4; ++k) {          // m=128 (L=1024)
    const int u = t + 256 * k;
    const int blk = u >> 7, j = u & 127;
    bfly8_dit(re, im, tw, blk * 1024 + j, 128, j, 8);
  }
  __syncthreads();
#pragma unroll
  for (int k = 0; k < 4; ++k) {          // m=1024 (L=8192)
    const int j = t + 256 * k;
    bfly8_dit(re, im, tw, j, 1024, j, 1);
  }
  __syncthreads();
}

// scrambled position of logical (N - f) given scrambled position p of f
__device__ inline int posN_minus(int p) {
  const int f = (p >> 10) | (((p >> 7) & 7) << 3) | (((p >> 4) & 7) << 6) |
                (((p >> 1) & 7) << 9) | ((p & 1) << 12);
  const int g = (NFFT - f) & (NFFT - 1);
  return ((g & 7) << 10) | (((g >> 3) & 7) << 7) | (((g >> 6) & 7) << 4) |
         (((g >> 9) & 7) << 1) | ((g >> 12) & 1);
}

// ---------------------------------------------------------------------------
__global__ __launch_bounds__(256) void qk_scores(const float* __restrict__ Qt,
                                                 const float* __restrict__ Kt,
                                                 const float2* __restrict__ tw,
                                                 float* __restrict__ sfft) {
  __shared__ float s_re[NFFT], s_im[NFFT];
  const int blk = blockIdx.x;  // 512
  const int bh = blk >> 4;
  const int d0 = (blk & 15) * 4;
  const int tid = threadIdx.x;
  float2 racc[32];
#pragma unroll
  for (int j = 0; j < 32; ++j) racc[j] = make_float2(0.f, 0.f);

  for (int ch = 0; ch < 4; ++ch) {
    const long long base = ((long long)bh * 64 + d0 + ch) * NFFT;
    if (ch) __syncthreads();
    for (int n = tid; n < NFFT; n += 256) {
      const int a = SW(n);
      s_re[a] = Qt[base + n];
      s_im[a] = Kt[base + n];
    }
    __syncthreads();
    fft_dif(s_re, s_im, tw);
#pragma unroll
    for (int j = 0; j < 32; ++j) {
      const int p = j * 256 + tid;
      const int sp = SW(p);
      const int p2 = posN_minus(p);
      const int sp2 = SW(p2);
      const float zr = s_re[sp], zi = s_im[sp];
      const float yr = s_re[sp2], yi = s_im[sp2];
      const float qr = 0.5f * (zr + yr), qi = 0.5f * (zi - yi);
      const float kr = 0.5f * (zi + yi), ki = -0.5f * (zr - yr);
      racc[j].x += qr * kr + qi * ki;
      racc[j].y += qi * kr - qr * ki;
    }
  }
  float* outp = sfft + (long long)bh * NFFT * 2;
#pragma unroll
  for (int j = 0; j < 32; ++j) {
    const int p = j * 256 + tid;
    atomicAdd(outp + 2 * p, racc[j].x);
    atomicAdd(outp + 2 * p + 1, racc[j].y);
  }
}

// ---------------------------------------------------------------------------
__global__ __launch_bounds__(256) void softmax_attn(const float* __restrict__ sfft,
                                                    const float2* __restrict__ tw,
                                                    float* __restrict__ attnF) {
  __shared__ float s_re[NFFT], s_im[NFFT];
  __shared__ float red[8];
  const int bh = blockIdx.x;
  const int tid = threadIdx.x;
  const float2* S = (const float2*)(sfft + (long long)bh * NFFT * 2);
  for (int p = tid; p < NFFT; p += 256) {
    const float2 z = S[p];
    const int a = SW(p);
    s_re[a] = z.x;
    s_im[a] = z.y;
  }
  __syncthreads();
  fft_dit(s_re, s_im, tw);   // scrambled -> natural scores (unscaled)
  const float cs = (1.0f / (float)NFFT) * 0.125f;  // 1/N * 1/sqrt(64)
  float lmax = -1e30f;
  for (int n = tid; n < NFFT; n += 256) {
    const int a = SW(n);
    const float v = s_re[a] * cs;
    s_re[a] = v;
    lmax = fmaxf(lmax, v);
  }
  for (int o = 32; o > 0; o >>= 1) lmax = fmaxf(lmax, __shfl_down(lmax, o, 64));
  if ((tid & 63) == 0) red[tid >> 6] = lmax;
  __syncthreads();
  const float m = fmaxf(fmaxf(red[0], red[1]), fmaxf(red[2], red[3]));
  float lsum = 0.f;
  for (int n = tid; n < NFFT; n += 256) {
    const int a = SW(n);
    const float e = expf(s_re[a] - m);
    s_re[a] = e;
    lsum += e;
  }
  for (int o = 32; o > 0; o >>= 1) lsum += __shfl_down(lsum, o, 64);
  if ((tid & 63) == 0) red[4 + (tid >> 6)] = lsum;
  __syncthreads();
  const float inv = 1.0f / (red[4] + red[5] + red[6] + red[7]);
  for (int n = tid; n < NFFT; n += 256) {
    const int a = SW(n);
    s_re[a] *= inv;
    s_im[a] = 0.f;
  }
  __syncthreads();
  fft_dif(s_re, s_im, tw);   // natural attn -> scrambled attnF
  float2* AF = (float2*)(attnF + (long long)bh * NFFT * 2);
  for (int p = tid; p < NFFT; p += 256) {
    const int a = SW(p);
    AF[p] = make_float2(s_re[a], s_im[a]);
  }
}

// ---------------------------------------------------------------------------
__global__ __launch_bounds__(256) void pv_out(const float* __restrict__ Vt,
                                              const float* __restrict__ attnF,
                                              const float2* __restrict__ tw,
                                              float* __restrict__ Ot) {
  __shared__ float s_re[NFFT], s_im[NFFT];
  const int blk = blockIdx.x;  // 1024 (d-pair)
  const long long base0 = (long long)blk * 2 * NFFT;
  const long long base1 = base0 + NFFT;
  const int bh = blk >> 5;
  const int tid = threadIdx.x;
  for (int n = tid; n < NFFT; n += 256) {
    const int a = SW(n);
    s_re[a] = Vt[base0 + n];
    s_im[a] = Vt[base1 + n];
  }
  __syncthreads();
  fft_dif(s_re, s_im, tw);
  const float2* AF = (const float2*)(attnF + (long long)bh * NFFT * 2);
  for (int p = tid; p < NFFT; p += 256) {
    const float2 a = AF[p];
    const int sp = SW(p);
    const float zr = s_re[sp], zi = s_im[sp];
    s_re[sp] = a.x * zr - a.y * zi;
    s_im[sp] = a.x * zi + a.y * zr;
  }
  __syncthreads();
  fft_dit(s_re, s_im, tw);
  const float s = 1.0f / (float)NFFT;
  for (int n = tid; n < NFFT; n += 256) {
    const int a = SW(n);
    Ot[base0 + n] = s_re[a] * s;
    Ot[base1 + n] = s_im[a] * s;
  }
}

// ---------------------------------------------------------------------------
extern "C" void kernel_launch(void* const* d_in, const int* in_sizes, int n_in,
                              void* d_out, int out_size, void* d_ws, size_t ws_size,
                              hipStream_t stream) {
  const float* x  = (const float*)d_in[0];
  const float* Wq = (const float*)d_in[1];
  const float* bq = (const float*)d_in[2];
  const float* Wk = (const float*)d_in[3];
  const float* bk = (const float*)d_in[4];
  const float* Wv = (const float*)d_in[5];
  const float* bv = (const float*)d_in[6];
  const float* Wo = (const float*)d_in[7];
  const float* bo = (const float*)d_in[8];
  float* out = (float*)d_out;
  float* ws = (float*)d_ws;

  const long long TSZ = (long long)2 * DMODEL * NSEQ;  // 16,777,216 floats
  float* Qt = ws;
  float* Kt = Qt + TSZ;
  float* sfft = Kt + TSZ;                       // 32*8192 complex (scrambled)
  float* attnF = sfft + (long long)32 * NFFT * 2;
  float2* tw = (float2*)(attnF + (long long)32 * NFFT * 2);   // 8192 float2
  u16* Wsp = (u16*)(tw + NFFT);                 // 8 x 1Mi u16
  const long long WSZ = (long long)DMODEL * DMODEL;
  u16* Wqh = Wsp + 0 * WSZ; u16* Wql = Wsp + 1 * WSZ;
  u16* Wkh = Wsp + 2 * WSZ; u16* Wkl = Wsp + 3 * WSZ;
  u16* Wvh = Wsp + 4 * WSZ; u16* Wvl = Wsp + 5 * WSZ;
  u16* Woh = Wsp + 6 * WSZ; u16* Wol = Wsp + 7 * WSZ;
  float* Vt = out;            // d_out as V scratch
  float* Ot = Qt;             // reuse Q buffer for O (transposed)
  u16* Oh = (u16*)Kt;         // reuse K buffer for split-O
  u16* Ol = Oh + TSZ;

  const dim3 blk(256);
  const int w4 = (int)(WSZ / 4);
  hipLaunchKernelGGL(split_f32, dim3(w4 / 256), blk, 0, stream, Wq, Wqh, Wql, w4);
  hipLaunchKernelGGL(split_f32, dim3(w4 / 256), blk, 0, stream, Wk, Wkh, Wkl, w4);
  hipLaunchKernelGGL(split_f32, dim3(w4 / 256), blk, 0, stream, Wv, Wvh, Wvl, w4);
  hipLaunchKernelGGL(split_f32, dim3(w4 / 256), blk, 0, stream, Wo, Woh, Wol, w4);
  hipLaunchKernelGGL(tw_init, dim3(NFFT / 256), blk, 0, stream, tw);
  hipMemsetAsync(sfft, 0, (size_t)32 * NFFT * 2 * sizeof(float), stream);

  const long long xBS = (long long)NSEQ * DMODEL;
  const long long tBS = (long long)DMODEL * NSEQ;

  // Projections: C[e][n] = sum_d W[e][d] * x[b][n][d]
  const dim3 gp(NSEQ / 128, DMODEL / 128, 2);
  hipLaunchKernelGGL((gemm_sp<1>), gp, blk, 0, stream,
                     Wqh, Wql, (long long)DMODEL, 0LL, (const void*)x, (const void*)nullptr,
                     (long long)DMODEL, xBS, bq, 1, Qt, (long long)NSEQ, tBS, DMODEL);
  hipLaunchKernelGGL((gemm_sp<1>), gp, blk, 0, stream,
                     Wkh, Wkl, (long long)DMODEL, 0LL, (const void*)x, (const void*)nullptr,
                     (long long)DMODEL, xBS, bk, 1, Kt, (long long)NSEQ, tBS, DMODEL);
  hipLaunchKernelGGL((gemm_sp<1>), gp, blk, 0, stream,
                     Wvh, Wvl, (long long)DMODEL, 0LL, (const void*)x, (const void*)nullptr,
                     (long long)DMODEL, xBS, bv, 1, Vt, (long long)NSEQ, tBS, DMODEL);

  hipLaunchKernelGGL(qk_scores, dim3(512), blk, 0, stream, Qt, Kt, tw, sfft);
  hipLaunchKernelGGL(softmax_attn, dim3(32), blk, 0, stream, sfft, tw, attnF);
  hipLaunchKernelGGL(pv_out, dim3(1024), blk, 0, stream, Vt, attnF, tw, Ot);

  hipLaunchKernelGGL(transp_split, dim3(NSEQ / 64, DMODEL / 64, 2), blk, 0, stream, Ot, Oh, Ol);

  // Final: out[b][n][e] = sum_d O[b][n][d] * Wo[e][d] + bo[e]
  const dim3 gf(DMODEL / 128, NSEQ / 128, 2);
  hipLaunchKernelGGL((gemm_sp<0>), gf, blk, 0, stream,
                     Oh, Ol, (long long)DMODEL, tBS, (const void*)Woh, (const void*)Wol,
                     (long long)DMODEL, 0LL, bo, 2, out, (long long)DMODEL, xBS, DMODEL);
}